// Round 1
// baseline (1124.239 us; speedup 1.0000x reference)
//
#include <hip/hip_runtime.h>
#include <math.h>

#define NB 2        // batch
#define NC 64       // channels
#define ND 8        // head dim (C/8)
#define NN 4096     // tokens (T*W*H)
#define NM 256      // landmarks
#define NL 16       // N/M
#define SCALE 0.35355339059327373f  // 1/sqrt(8)

// ---------------- qkv projection ----------------
// x: [B][C][N]; q,k: [B][N][D]; v: [B][C][N]
__global__ __launch_bounds__(256) void qkv_kernel(
    const float* __restrict__ x,
    const float* __restrict__ wq, const float* __restrict__ bq,
    const float* __restrict__ wk, const float* __restrict__ bk,
    const float* __restrict__ wv, const float* __restrict__ bv,
    float* __restrict__ q, float* __restrict__ k, float* __restrict__ v) {
  __shared__ float swq[ND][NC], swk[ND][NC], swv[NC][NC];
  int t = threadIdx.x;
  for (int i = t; i < ND * NC; i += 256) { swq[i / NC][i % NC] = wq[i]; swk[i / NC][i % NC] = wk[i]; }
  for (int i = t; i < NC * NC; i += 256) swv[i / NC][i % NC] = wv[i];
  __syncthreads();
  int gid = blockIdx.x * 256 + t;   // global token id over B*N
  int b = gid / NN, n = gid % NN;
  float xc[NC];
  #pragma unroll
  for (int c = 0; c < NC; ++c) xc[c] = x[((size_t)b * NC + c) * NN + n];
  #pragma unroll
  for (int o = 0; o < ND; ++o) {
    float aq = bq[o], ak = bk[o];
    #pragma unroll
    for (int c = 0; c < NC; ++c) { aq += swq[o][c] * xc[c]; ak += swk[o][c] * xc[c]; }
    q[((size_t)b * NN + n) * ND + o] = aq;
    k[((size_t)b * NN + n) * ND + o] = ak;
  }
  for (int o = 0; o < NC; ++o) {
    float a = bv[o];
    #pragma unroll
    for (int c = 0; c < NC; ++c) a += swv[o][c] * xc[c];
    v[((size_t)b * NC + o) * NN + n] = a;
  }
}

// ---------------- landmarks (mean over L=16 tokens) ----------------
__global__ void landmark_kernel(const float* __restrict__ q, const float* __restrict__ k,
                                float* __restrict__ ql, float* __restrict__ kl) {
  int idx = blockIdx.x * 256 + threadIdx.x;   // over B*M*D
  int b = idx / (NM * ND), r = idx % (NM * ND), i = r / ND, o = r % ND;
  float sq = 0.f, sk = 0.f;
  for (int l = 0; l < NL; ++l) {
    size_t base = ((size_t)b * NN + i * NL + l) * ND + o;
    sq += q[base]; sk += k[base];
  }
  ql[idx] = sq * (1.0f / NL);
  kl[idx] = sk * (1.0f / NL);
}

// ---------------- softmax rows vs landmarks (k1 and k2) ----------------
// Q: [B][R][D]; KL: [B][M][D]; out: [B][R][M].  One wave per row, 4 rows/block.
__global__ __launch_bounds__(256) void scores_softmax_m(
    const float* __restrict__ Q, int R, const float* __restrict__ KL,
    float* __restrict__ out) {
  __shared__ float skl[NM][9];
  int b = blockIdx.y;
  int t = threadIdx.x;
  for (int i = t; i < NM * ND; i += 256) skl[i >> 3][i & 7] = KL[(size_t)b * NM * ND + i];
  __syncthreads();
  int wave = t >> 6, lane = t & 63;
  int r = blockIdx.x * 4 + wave;
  const float* qrow = Q + ((size_t)b * R + r) * ND;
  float qr[ND];
  #pragma unroll
  for (int dd = 0; dd < ND; ++dd) qr[dd] = qrow[dd];
  float sc[4];
  float lmax = -1e30f;
  #pragma unroll
  for (int s = 0; s < 4; ++s) {
    int j = lane + 64 * s;
    float a = 0.f;
    #pragma unroll
    for (int dd = 0; dd < ND; ++dd) a += qr[dd] * skl[j][dd];
    sc[s] = a * SCALE;
    lmax = fmaxf(lmax, sc[s]);
  }
  for (int off = 32; off; off >>= 1) lmax = fmaxf(lmax, __shfl_xor(lmax, off));
  float lsum = 0.f;
  #pragma unroll
  for (int s = 0; s < 4; ++s) { sc[s] = expf(sc[s] - lmax); lsum += sc[s]; }
  for (int off = 32; off; off >>= 1) lsum += __shfl_xor(lsum, off);
  float inv = 1.0f / lsum;
  #pragma unroll
  for (int s = 0; s < 4; ++s) out[((size_t)b * R + r) * NM + lane + 64 * s] = sc[s] * inv;
}

// ---------------- k3: softmax rows (landmark queries) vs full keys ----------------
// QL: [B][M][D]; K: [B][N][D]; out: [B][M][N]. One block per row.
__global__ __launch_bounds__(256) void scores_softmax_n(
    const float* __restrict__ QL, const float* __restrict__ Kt,
    float* __restrict__ out) {
  __shared__ float wred[4], wsum[4];
  int b = blockIdx.y, i = blockIdx.x;
  int t = threadIdx.x;
  float qr[ND];
  #pragma unroll
  for (int dd = 0; dd < ND; ++dd) qr[dd] = QL[((size_t)b * NM + i) * ND + dd];
  float sc[16];
  float lmax = -1e30f;
  #pragma unroll
  for (int s = 0; s < 16; ++s) {
    int n = t + 256 * s;
    const float* kp = Kt + ((size_t)b * NN + n) * ND;
    float a = 0.f;
    #pragma unroll
    for (int dd = 0; dd < ND; ++dd) a += qr[dd] * kp[dd];
    sc[s] = a * SCALE;
    lmax = fmaxf(lmax, sc[s]);
  }
  for (int off = 32; off; off >>= 1) lmax = fmaxf(lmax, __shfl_xor(lmax, off));
  if ((t & 63) == 0) wred[t >> 6] = lmax;
  __syncthreads();
  lmax = fmaxf(fmaxf(wred[0], wred[1]), fmaxf(wred[2], wred[3]));
  float lsum = 0.f;
  #pragma unroll
  for (int s = 0; s < 16; ++s) { sc[s] = expf(sc[s] - lmax); lsum += sc[s]; }
  for (int off = 32; off; off >>= 1) lsum += __shfl_xor(lsum, off);
  if ((t & 63) == 0) wsum[t >> 6] = lsum;
  __syncthreads();
  lsum = wsum[0] + wsum[1] + wsum[2] + wsum[3];
  float inv = 1.0f / lsum;
  #pragma unroll
  for (int s = 0; s < 16; ++s) out[((size_t)b * NM + i) * NN + t + 256 * s] = sc[s] * inv;
}

// ---------------- denom = 1 / (max colsum * max rowsum) over batch ----------------
__global__ void denom_kernel(const float* __restrict__ k2, float* __restrict__ denom) {
  __shared__ float redc[256], redr[256];
  int t = threadIdx.x;
  float mc = -1e30f, mr = -1e30f;
  for (int b = 0; b < NB; ++b) {
    float cs = 0.f, rs = 0.f;
    for (int i = 0; i < NM; ++i) {
      cs += k2[((size_t)b * NM + i) * NM + t];
      rs += k2[((size_t)b * NM + t) * NM + i];
    }
    mc = fmaxf(mc, cs); mr = fmaxf(mr, rs);
  }
  redc[t] = mc; redr[t] = mr;
  __syncthreads();
  for (int off = 128; off; off >>= 1) {
    if (t < off) {
      redc[t] = fmaxf(redc[t], redc[t + off]);
      redr[t] = fmaxf(redr[t], redr[t + off]);
    }
    __syncthreads();
  }
  if (t == 0) denom[0] = 1.0f / (redc[0] * redr[0]);
}

// ---------------- V0 = K^T * invdenom ----------------
__global__ void vinit_kernel(const float* __restrict__ k2, const float* __restrict__ denom,
                             float* __restrict__ V) {
  int idx = blockIdx.x * 256 + threadIdx.x;  // over B*M*M
  int b = idx / (NM * NM), r = idx % (NM * NM), i = r / NM, j = r % NM;
  V[idx] = k2[((size_t)b * NM + j) * NM + i] * denom[0];
}

// ---------------- generic batched GEMM: out = s_a*A + s_ab*(A @ Bm) ----------------
// A: [B][R][256], Bm: [B][256][256], out: [B][R][256]
__global__ __launch_bounds__(256) void gemm_rk(
    const float* __restrict__ A, const float* __restrict__ Bm,
    float* __restrict__ out, int R, float s_a, float s_ab) {
  int b = blockIdx.z;
  int bi = blockIdx.y * 64, bj = blockIdx.x * 64;
  __shared__ float As[16][68];   // transposed A tile: As[kk][row]
  __shared__ float Bs[16][72];   // Bs[kk][col]
  int t = threadIdx.x;
  int tx = t & 15, ty = t >> 4;
  const float* Ab = A + (size_t)b * R * NM;
  const float* Bb = Bm + (size_t)b * NM * NM;
  float acc[4][4] = {};
  int lrow = t >> 2, lkc = (t & 3) << 2;
  int lkr = t >> 4, lc4 = (t & 15) << 2;
  for (int k0 = 0; k0 < NM; k0 += 16) {
    float4 av = *(const float4*)(Ab + (size_t)(bi + lrow) * NM + k0 + lkc);
    float4 bv = *(const float4*)(Bb + (size_t)(k0 + lkr) * NM + bj + lc4);
    As[lkc + 0][lrow] = av.x;
    As[lkc + 1][lrow] = av.y;
    As[lkc + 2][lrow] = av.z;
    As[lkc + 3][lrow] = av.w;
    *(float4*)&Bs[lkr][lc4] = bv;
    __syncthreads();
    #pragma unroll
    for (int kk = 0; kk < 16; ++kk) {
      float4 a4 = *(const float4*)&As[kk][ty << 2];
      float4 b4 = *(const float4*)&Bs[kk][tx << 2];
      float av_[4] = {a4.x, a4.y, a4.z, a4.w};
      float bv_[4] = {b4.x, b4.y, b4.z, b4.w};
      #pragma unroll
      for (int i = 0; i < 4; ++i)
        #pragma unroll
        for (int j = 0; j < 4; ++j) acc[i][j] += av_[i] * bv_[j];
    }
    __syncthreads();
  }
  #pragma unroll
  for (int i = 0; i < 4; ++i) {
    size_t o = ((size_t)b * R + bi + (ty << 2) + i) * NM + bj + (tx << 2);
    float4 r;
    r.x = s_ab * acc[i][0]; r.y = s_ab * acc[i][1];
    r.z = s_ab * acc[i][2]; r.w = s_ab * acc[i][3];
    if (s_a != 0.0f) {
      float4 a0 = *(const float4*)(A + o);
      r.x += s_a * a0.x; r.y += s_a * a0.y; r.z += s_a * a0.z; r.w += s_a * a0.w;
    }
    *(float4*)(out + o) = r;
  }
}

// ---------------- attn = Abuf @ k3 -> [B][N][N] ----------------
__global__ __launch_bounds__(256) void gemm_attn(
    const float* __restrict__ A, const float* __restrict__ K3,
    float* __restrict__ attn) {
  int b = blockIdx.z;
  int bi = blockIdx.y * 64, bj = blockIdx.x * 64;
  __shared__ float As[16][68];
  __shared__ float Bs[16][72];
  int t = threadIdx.x;
  int tx = t & 15, ty = t >> 4;
  const float* Ab = A + (size_t)b * NN * NM;
  const float* Bb = K3 + (size_t)b * NM * NN;
  float acc[4][4] = {};
  int lrow = t >> 2, lkc = (t & 3) << 2;
  int lkr = t >> 4, lc4 = (t & 15) << 2;
  for (int k0 = 0; k0 < NM; k0 += 16) {
    float4 av = *(const float4*)(Ab + (size_t)(bi + lrow) * NM + k0 + lkc);
    float4 bv = *(const float4*)(Bb + (size_t)(k0 + lkr) * NN + bj + lc4);
    As[lkc + 0][lrow] = av.x;
    As[lkc + 1][lrow] = av.y;
    As[lkc + 2][lrow] = av.z;
    As[lkc + 3][lrow] = av.w;
    *(float4*)&Bs[lkr][lc4] = bv;
    __syncthreads();
    #pragma unroll
    for (int kk = 0; kk < 16; ++kk) {
      float4 a4 = *(const float4*)&As[kk][ty << 2];
      float4 b4 = *(const float4*)&Bs[kk][tx << 2];
      float av_[4] = {a4.x, a4.y, a4.z, a4.w};
      float bv_[4] = {b4.x, b4.y, b4.z, b4.w};
      #pragma unroll
      for (int i = 0; i < 4; ++i)
        #pragma unroll
        for (int j = 0; j < 4; ++j) acc[i][j] += av_[i] * bv_[j];
    }
    __syncthreads();
  }
  #pragma unroll
  for (int i = 0; i < 4; ++i) {
    size_t o = ((size_t)b * NN + bi + (ty << 2) + i) * NN + bj + (tx << 2);
    float4 r;
    r.x = acc[i][0]; r.y = acc[i][1]; r.z = acc[i][2]; r.w = acc[i][3];
    *(float4*)(attn + o) = r;
  }
}

// ---------------- kv[b][p][c] = sum_j k3[b][p][j] * v[b][c][j] ----------------
__global__ __launch_bounds__(256) void kv_kernel(
    const float* __restrict__ K3, const float* __restrict__ Vv,
    float* __restrict__ kvout) {
  int b = blockIdx.z, bp = blockIdx.x * 64;
  __shared__ float Ks[64][36], Vs[64][36];
  int t = threadIdx.x, tx = t & 15, ty = t >> 4;
  int lrow = t >> 2, ljc = (t & 3) * 8;
  float acc[4][4] = {};
  for (int j0 = 0; j0 < NN; j0 += 32) {
    float4 a0 = *(const float4*)(K3 + ((size_t)b * NM + bp + lrow) * NN + j0 + ljc);
    float4 a1 = *(const float4*)(K3 + ((size_t)b * NM + bp + lrow) * NN + j0 + ljc + 4);
    float4 v0 = *(const float4*)(Vv + ((size_t)b * NC + lrow) * NN + j0 + ljc);
    float4 v1 = *(const float4*)(Vv + ((size_t)b * NC + lrow) * NN + j0 + ljc + 4);
    *(float4*)&Ks[lrow][ljc] = a0;
    *(float4*)&Ks[lrow][ljc + 4] = a1;
    *(float4*)&Vs[lrow][ljc] = v0;
    *(float4*)&Vs[lrow][ljc + 4] = v1;
    __syncthreads();
    #pragma unroll
    for (int kk = 0; kk < 32; ++kk) {
      float av_[4], bv_[4];
      #pragma unroll
      for (int i = 0; i < 4; ++i) av_[i] = Ks[(ty << 2) + i][kk];
      #pragma unroll
      for (int j = 0; j < 4; ++j) bv_[j] = Vs[(tx << 2) + j][kk];
      #pragma unroll
      for (int i = 0; i < 4; ++i)
        #pragma unroll
        for (int j = 0; j < 4; ++j) acc[i][j] += av_[i] * bv_[j];
    }
    __syncthreads();
  }
  #pragma unroll
  for (int i = 0; i < 4; ++i)
    #pragma unroll
    for (int j = 0; j < 4; ++j)
      kvout[((size_t)b * NM + bp + (ty << 2) + i) * NC + (tx << 2) + j] = acc[i][j];
}

// ---------------- out[b][c][n] = gamma * (A[b][n][:] . kv[b][:][c]) + x[b][c][n] ----------------
__global__ __launch_bounds__(256) void out_kernel(
    const float* __restrict__ Ab, const float* __restrict__ kvm,
    const float* __restrict__ x, const float* __restrict__ gamma,
    float* __restrict__ outp) {
  __shared__ float As[32 * 256];   // swizzled
  int blk = blockIdx.x;             // B * N/32
  int b = blk / (NN / 32), n0 = (blk % (NN / 32)) * 32;
  int t = threadIdx.x;
  for (int it = 0; it < 32; ++it)
    As[it * 256 + (t ^ (it & 31))] = Ab[((size_t)b * NN + n0 + it) * NM + t];
  __syncthreads();
  int tn = t & 31, cg0 = (t >> 5) * 8;
  float g = gamma[0];
  float acc[8] = {};
  for (int p = 0; p < NM; ++p) {
    float a = As[tn * 256 + (p ^ (tn & 31))];
    #pragma unroll
    for (int qd = 0; qd < 8; ++qd) acc[qd] += a * kvm[((size_t)b * NM + p) * NC + cg0 + qd];
  }
  #pragma unroll
  for (int qd = 0; qd < 8; ++qd) {
    int c = cg0 + qd;
    size_t idx = ((size_t)b * NC + c) * NN + n0 + tn;
    outp[idx] = g * acc[qd] + x[idx];
  }
}

extern "C" void kernel_launch(void* const* d_in, const int* in_sizes, int n_in,
                              void* d_out, int out_size, void* d_ws, size_t ws_size,
                              hipStream_t stream) {
  const float* x     = (const float*)d_in[0];
  const float* wq    = (const float*)d_in[1];
  const float* bq    = (const float*)d_in[2];
  const float* wk    = (const float*)d_in[3];
  const float* bk    = (const float*)d_in[4];
  const float* wv    = (const float*)d_in[5];
  const float* bv    = (const float*)d_in[6];
  const float* gamma = (const float*)d_in[7];
  float* outp = (float*)d_out;                       // [B][C][N]
  float* attn = outp + (size_t)NB * NC * NN;         // [B][N][N]
  float* w = (float*)d_ws;

  float* qw   = w;                 // [B][N][D]    65536
  float* kw   = qw + 65536;        // [B][N][D]    65536
  float* vw   = kw + 65536;        // [B][C][N]    524288
  float* qlw  = vw + 524288;       // [B][M][D]    4096
  float* klw  = qlw + 4096;        // [B][M][D]    4096
  float* k1w  = klw + 4096;        // [B][N][M]    2097152
  float* k2w  = k1w + 2097152;     // [B][M][M]    131072
  float* k3w  = k2w + 131072;      // [B][M][N]    2097152
  float* Abuf = k3w + 2097152;     // [B][N][M]    2097152
  float* Va   = Abuf + 2097152;    // [B][M][M]    131072
  float* Vb   = Va + 131072;       // [B][M][M]    131072
  float* Zb   = Vb + 131072;       // [B][M][M]    131072
  float* T1   = Zb + 131072;       // [B][M][M]    131072
  float* T2   = T1 + 131072;       // [B][M][M]    131072
  float* kvw  = T2 + 131072;       // [B][M][C]    32768
  float* denw = kvw + 32768;       // [1]

  qkv_kernel<<<dim3(NB * NN / 256), dim3(256), 0, stream>>>(x, wq, bq, wk, bk, wv, bv, qw, kw, vw);
  landmark_kernel<<<dim3(NB * NM * ND / 256), dim3(256), 0, stream>>>(qw, kw, qlw, klw);
  scores_softmax_m<<<dim3(NN / 4, NB), dim3(256), 0, stream>>>(qw, NN, klw, k1w);
  scores_softmax_m<<<dim3(NM / 4, NB), dim3(256), 0, stream>>>(qlw, NM, klw, k2w);
  scores_softmax_n<<<dim3(NM, NB), dim3(256), 0, stream>>>(qlw, kw, k3w);
  denom_kernel<<<dim3(1), dim3(256), 0, stream>>>(k2w, denw);
  vinit_kernel<<<dim3(NB * NM * NM / 256), dim3(256), 0, stream>>>(k2w, denw, Va);

  float* Vc = Va; float* Vn = Vb;
  for (int it = 0; it < 6; ++it) {
    gemm_rk<<<dim3(4, 4, NB), dim3(256), 0, stream>>>(k2w, Vc, Zb, NM, 0.f, 1.f);    // Z = K@V
    gemm_rk<<<dim3(4, 4, NB), dim3(256), 0, stream>>>(Zb, Zb, T1, NM, 7.f, -1.f);    // T1 = 7Z - Z@Z
    gemm_rk<<<dim3(4, 4, NB), dim3(256), 0, stream>>>(Zb, T1, T2, NM, 15.f, -1.f);   // T2 = 15Z - Z@T1
    gemm_rk<<<dim3(4, 4, NB), dim3(256), 0, stream>>>(Vc, T2, Vn, NM, 3.25f, -0.25f);// V' = 3.25V - 0.25 V@T2
    float* tmp = Vc; Vc = Vn; Vn = tmp;
  }

  gemm_rk<<<dim3(4, NN / 64, NB), dim3(256), 0, stream>>>(k1w, Vc, Abuf, NN, 0.f, 1.f); // A = k1 @ Vinv
  gemm_attn<<<dim3(NN / 64, NN / 64, NB), dim3(256), 0, stream>>>(Abuf, k3w, attn);     // attn = A @ k3
  kv_kernel<<<dim3(NM / 64, 1, NB), dim3(256), 0, stream>>>(k3w, vw, kvw);              // kv = k3 @ v^T
  out_kernel<<<dim3(NB * NN / 32), dim3(256), 0, stream>>>(Abuf, kvw, x, gamma, outp);  // out = g*(A@kv)+x
}

// Round 2
// 414.445 us; speedup vs baseline: 2.7126x; 2.7126x over previous
//
#include <hip/hip_runtime.h>
#include <hip/hip_bf16.h>
#include <math.h>

#define NB 2        // batch
#define NC 64       // channels
#define ND 8        // head dim (C/8)
#define NN 4096     // tokens (T*W*H)
#define NM 256      // landmarks
#define NL 16       // N/M
#define SCALE 0.35355339059327373f  // 1/sqrt(8)

typedef __attribute__((ext_vector_type(4))) float f32x4;
typedef __attribute__((ext_vector_type(8))) short bf16x8;
typedef __attribute__((ext_vector_type(4))) int int4v;

__device__ inline ushort f2bf(float f) {
  __hip_bfloat16 h = __float2bfloat16(f);
  return *reinterpret_cast<ushort*>(&h);
}

// ---------------- qkv projection ----------------
__global__ __launch_bounds__(256) void qkv_kernel(
    const float* __restrict__ x,
    const float* __restrict__ wq, const float* __restrict__ bq,
    const float* __restrict__ wk, const float* __restrict__ bk,
    const float* __restrict__ wv, const float* __restrict__ bv,
    float* __restrict__ q, float* __restrict__ k, float* __restrict__ v) {
  __shared__ float swq[ND][NC], swk[ND][NC], swv[NC][NC];
  int t = threadIdx.x;
  for (int i = t; i < ND * NC; i += 256) { swq[i / NC][i % NC] = wq[i]; swk[i / NC][i % NC] = wk[i]; }
  for (int i = t; i < NC * NC; i += 256) swv[i / NC][i % NC] = wv[i];
  __syncthreads();
  int gid = blockIdx.x * 256 + t;
  int b = gid / NN, n = gid % NN;
  float xc[NC];
  #pragma unroll
  for (int c = 0; c < NC; ++c) xc[c] = x[((size_t)b * NC + c) * NN + n];
  #pragma unroll
  for (int o = 0; o < ND; ++o) {
    float aq = bq[o], ak = bk[o];
    #pragma unroll
    for (int c = 0; c < NC; ++c) { aq += swq[o][c] * xc[c]; ak += swk[o][c] * xc[c]; }
    q[((size_t)b * NN + n) * ND + o] = aq;
    k[((size_t)b * NN + n) * ND + o] = ak;
  }
  for (int o = 0; o < NC; ++o) {
    float a = bv[o];
    #pragma unroll
    for (int c = 0; c < NC; ++c) a += swv[o][c] * xc[c];
    v[((size_t)b * NC + o) * NN + n] = a;
  }
}

// ---------------- landmarks ----------------
__global__ void landmark_kernel(const float* __restrict__ q, const float* __restrict__ k,
                                float* __restrict__ ql, float* __restrict__ kl) {
  int idx = blockIdx.x * 256 + threadIdx.x;
  int b = idx / (NM * ND), r = idx % (NM * ND), i = r / ND, o = r % ND;
  float sq = 0.f, sk = 0.f;
  for (int l = 0; l < NL; ++l) {
    size_t base = ((size_t)b * NN + i * NL + l) * ND + o;
    sq += q[base]; sk += k[base];
  }
  ql[idx] = sq * (1.0f / NL);
  kl[idx] = sk * (1.0f / NL);
}

// ---------------- softmax rows vs landmarks (k1 and k2) ----------------
__global__ __launch_bounds__(256) void scores_softmax_m(
    const float* __restrict__ Q, int R, const float* __restrict__ KL,
    float* __restrict__ out) {
  __shared__ float skl[NM][9];
  int b = blockIdx.y;
  int t = threadIdx.x;
  for (int i = t; i < NM * ND; i += 256) skl[i >> 3][i & 7] = KL[(size_t)b * NM * ND + i];
  __syncthreads();
  int wave = t >> 6, lane = t & 63;
  int r = blockIdx.x * 4 + wave;
  const float* qrow = Q + ((size_t)b * R + r) * ND;
  float qr[ND];
  #pragma unroll
  for (int dd = 0; dd < ND; ++dd) qr[dd] = qrow[dd];
  float sc[4];
  float lmax = -1e30f;
  #pragma unroll
  for (int s = 0; s < 4; ++s) {
    int j = lane + 64 * s;
    float a = 0.f;
    #pragma unroll
    for (int dd = 0; dd < ND; ++dd) a += qr[dd] * skl[j][dd];
    sc[s] = a * SCALE;
    lmax = fmaxf(lmax, sc[s]);
  }
  for (int off = 32; off; off >>= 1) lmax = fmaxf(lmax, __shfl_xor(lmax, off));
  float lsum = 0.f;
  #pragma unroll
  for (int s = 0; s < 4; ++s) { sc[s] = expf(sc[s] - lmax); lsum += sc[s]; }
  for (int off = 32; off; off >>= 1) lsum += __shfl_xor(lsum, off);
  float inv = 1.0f / lsum;
  #pragma unroll
  for (int s = 0; s < 4; ++s) out[((size_t)b * R + r) * NM + lane + 64 * s] = sc[s] * inv;
}

// ---------------- k3 softmax ----------------
__global__ __launch_bounds__(256) void scores_softmax_n(
    const float* __restrict__ QL, const float* __restrict__ Kt,
    float* __restrict__ out) {
  __shared__ float wred[4], wsum[4];
  int b = blockIdx.y, i = blockIdx.x;
  int t = threadIdx.x;
  float qr[ND];
  #pragma unroll
  for (int dd = 0; dd < ND; ++dd) qr[dd] = QL[((size_t)b * NM + i) * ND + dd];
  float sc[16];
  float lmax = -1e30f;
  #pragma unroll
  for (int s = 0; s < 16; ++s) {
    int n = t + 256 * s;
    const float* kp = Kt + ((size_t)b * NN + n) * ND;
    float a = 0.f;
    #pragma unroll
    for (int dd = 0; dd < ND; ++dd) a += qr[dd] * kp[dd];
    sc[s] = a * SCALE;
    lmax = fmaxf(lmax, sc[s]);
  }
  for (int off = 32; off; off >>= 1) lmax = fmaxf(lmax, __shfl_xor(lmax, off));
  if ((t & 63) == 0) wred[t >> 6] = lmax;
  __syncthreads();
  lmax = fmaxf(fmaxf(wred[0], wred[1]), fmaxf(wred[2], wred[3]));
  float lsum = 0.f;
  #pragma unroll
  for (int s = 0; s < 16; ++s) { sc[s] = expf(sc[s] - lmax); lsum += sc[s]; }
  for (int off = 32; off; off >>= 1) lsum += __shfl_xor(lsum, off);
  if ((t & 63) == 0) wsum[t >> 6] = lsum;
  __syncthreads();
  lsum = wsum[0] + wsum[1] + wsum[2] + wsum[3];
  float inv = 1.0f / lsum;
  #pragma unroll
  for (int s = 0; s < 16; ++s) out[((size_t)b * NM + i) * NN + t + 256 * s] = sc[s] * inv;
}

// ---------------- denom ----------------
__global__ void denom_kernel(const float* __restrict__ k2, float* __restrict__ denom) {
  __shared__ float redc[256], redr[256];
  int t = threadIdx.x;
  float mc = -1e30f, mr = -1e30f;
  for (int b = 0; b < NB; ++b) {
    float cs = 0.f, rs = 0.f;
    for (int i = 0; i < NM; ++i) {
      cs += k2[((size_t)b * NM + i) * NM + t];
      rs += k2[((size_t)b * NM + t) * NM + i];
    }
    mc = fmaxf(mc, cs); mr = fmaxf(mr, rs);
  }
  redc[t] = mc; redr[t] = mr;
  __syncthreads();
  for (int off = 128; off; off >>= 1) {
    if (t < off) {
      redc[t] = fmaxf(redc[t], redc[t + off]);
      redr[t] = fmaxf(redr[t], redr[t + off]);
    }
    __syncthreads();
  }
  if (t == 0) denom[0] = 1.0f / (redc[0] * redr[0]);
}

// ---------------- V0 = K^T * invdenom ----------------
__global__ void vinit_kernel(const float* __restrict__ k2, const float* __restrict__ denom,
                             float* __restrict__ V) {
  int idx = blockIdx.x * 256 + threadIdx.x;
  int b = idx / (NM * NM), r = idx % (NM * NM), i = r / NM, j = r % NM;
  V[idx] = k2[((size_t)b * NM + j) * NM + i] * denom[0];
}

// ---------------- 32x32-tile batched GEMM for the NS chain ----------------
// out = s_a*A + s_ab*(A @ Bm);  A,Bm,out: [B][256][256]; grid (8,8,B)
__global__ __launch_bounds__(256) void gemm_rk32(
    const float* __restrict__ A, const float* __restrict__ Bm,
    float* __restrict__ out, float s_a, float s_ab) {
  int b = blockIdx.z;
  int bi = blockIdx.y * 32, bj = blockIdx.x * 32;
  __shared__ float As[32][33], Bs[32][33];
  int t = threadIdx.x;
  int lr = t >> 3, lc = (t & 7) * 4;
  const float* Ab = A + (size_t)b * NM * NM;
  const float* Bb = Bm + (size_t)b * NM * NM;
  float acc[2][2] = {};
  int tx = t & 15, ty = t >> 4;
  for (int k0 = 0; k0 < NM; k0 += 32) {
    float4 av = *(const float4*)(Ab + (size_t)(bi + lr) * NM + k0 + lc);
    float4 bv = *(const float4*)(Bb + (size_t)(k0 + lr) * NM + bj + lc);
    As[lr][lc] = av.x; As[lr][lc + 1] = av.y; As[lr][lc + 2] = av.z; As[lr][lc + 3] = av.w;
    Bs[lr][lc] = bv.x; Bs[lr][lc + 1] = bv.y; Bs[lr][lc + 2] = bv.z; Bs[lr][lc + 3] = bv.w;
    __syncthreads();
    #pragma unroll
    for (int kk = 0; kk < 32; ++kk) {
      float a0 = As[ty * 2][kk], a1 = As[ty * 2 + 1][kk];
      float b0 = Bs[kk][tx * 2], b1 = Bs[kk][tx * 2 + 1];
      acc[0][0] += a0 * b0; acc[0][1] += a0 * b1;
      acc[1][0] += a1 * b0; acc[1][1] += a1 * b1;
    }
    __syncthreads();
  }
  #pragma unroll
  for (int i = 0; i < 2; ++i)
    #pragma unroll
    for (int j = 0; j < 2; ++j) {
      size_t o = ((size_t)b * NM + bi + ty * 2 + i) * NM + bj + tx * 2 + j;
      float r = s_ab * acc[i][j];
      if (s_a != 0.0f) r += s_a * A[o];
      out[o] = r;
    }
}

// ---------------- 64x64-tile GEMM (A = k1 @ Vinv) ----------------
__global__ __launch_bounds__(256) void gemm_rk(
    const float* __restrict__ A, const float* __restrict__ Bm,
    float* __restrict__ out, int R, float s_a, float s_ab) {
  int b = blockIdx.z;
  int bi = blockIdx.y * 64, bj = blockIdx.x * 64;
  __shared__ float As[16][68];
  __shared__ float Bs[16][72];
  int t = threadIdx.x;
  int tx = t & 15, ty = t >> 4;
  const float* Ab = A + (size_t)b * R * NM;
  const float* Bb = Bm + (size_t)b * NM * NM;
  float acc[4][4] = {};
  int lrow = t >> 2, lkc = (t & 3) << 2;
  int lkr = t >> 4, lc4 = (t & 15) << 2;
  for (int k0 = 0; k0 < NM; k0 += 16) {
    float4 av = *(const float4*)(Ab + (size_t)(bi + lrow) * NM + k0 + lkc);
    float4 bv = *(const float4*)(Bb + (size_t)(k0 + lkr) * NM + bj + lc4);
    As[lkc + 0][lrow] = av.x;
    As[lkc + 1][lrow] = av.y;
    As[lkc + 2][lrow] = av.z;
    As[lkc + 3][lrow] = av.w;
    *(float4*)&Bs[lkr][lc4] = bv;
    __syncthreads();
    #pragma unroll
    for (int kk = 0; kk < 16; ++kk) {
      float4 a4 = *(const float4*)&As[kk][ty << 2];
      float4 b4 = *(const float4*)&Bs[kk][tx << 2];
      float av_[4] = {a4.x, a4.y, a4.z, a4.w};
      float bv_[4] = {b4.x, b4.y, b4.z, b4.w};
      #pragma unroll
      for (int i = 0; i < 4; ++i)
        #pragma unroll
        for (int j = 0; j < 4; ++j) acc[i][j] += av_[i] * bv_[j];
    }
    __syncthreads();
  }
  #pragma unroll
  for (int i = 0; i < 4; ++i) {
    size_t o = ((size_t)b * R + bi + (ty << 2) + i) * NM + bj + (tx << 2);
    float4 r;
    r.x = s_ab * acc[i][0]; r.y = s_ab * acc[i][1];
    r.z = s_ab * acc[i][2]; r.w = s_ab * acc[i][3];
    if (s_a != 0.0f) {
      float4 a0 = *(const float4*)(A + o);
      r.x += s_a * a0.x; r.y += s_a * a0.y; r.z += s_a * a0.z; r.w += s_a * a0.w;
    }
    *(float4*)(out + o) = r;
  }
}

// ---------------- converts: fp32 -> bf16 (straight + transpose) ----------------
__global__ void cvt_bf16_kernel(const float* __restrict__ in, ushort* __restrict__ outp) {
  size_t idx = ((size_t)blockIdx.x * 256 + threadIdx.x) * 4;
  float4 v = *(const float4*)(in + idx);
  ushort4 u;
  u.x = f2bf(v.x); u.y = f2bf(v.y); u.z = f2bf(v.z); u.w = f2bf(v.w);
  *(ushort4*)(outp + idx) = u;
}

// k3: [B][NM][NN] fp32 -> k3t: [B][NN][NM] bf16
__global__ __launch_bounds__(256) void cvt_t_kernel(const float* __restrict__ k3,
                                                    ushort* __restrict__ k3t) {
  int b = blockIdx.z;
  int n0 = blockIdx.x * 32, m0 = blockIdx.y * 32;
  __shared__ float tile[32][33];
  int t = threadIdx.x;
  int r = t >> 3, c4 = (t & 7) * 4;
  float4 v = *(const float4*)(k3 + ((size_t)b * NM + m0 + r) * NN + n0 + c4);
  tile[c4][r] = v.x; tile[c4 + 1][r] = v.y; tile[c4 + 2][r] = v.z; tile[c4 + 3][r] = v.w;
  __syncthreads();
  ushort4 u;
  u.x = f2bf(tile[r][c4]);     u.y = f2bf(tile[r][c4 + 1]);
  u.z = f2bf(tile[r][c4 + 2]); u.w = f2bf(tile[r][c4 + 3]);
  *(ushort4*)(k3t + ((size_t)b * NN + n0 + r) * NM + m0 + c4) = u;
}

// ---------------- attn = A @ k3 via bf16 MFMA, 128x128 tile ----------------
// Abf: [B][NN][NM] bf16 row-major; K3T: [B][NN][NM] bf16 (j-major, i.e. k3^T)
__global__ __launch_bounds__(256) void gemm_attn_mfma(
    const ushort* __restrict__ Abf, const ushort* __restrict__ K3T,
    float* __restrict__ attn) {
  int b = blockIdx.z;
  int bi = blockIdx.y * 128, bj = blockIdx.x * 128;
  __shared__ ushort As[128 * 64];   // [row][k] bf16, XOR-swizzled rows
  __shared__ ushort Bs[128 * 64];   // [j][k]   bf16, XOR-swizzled
  int t = threadIdx.x;
  int wave = t >> 6, lane = t & 63;
  int wr = wave >> 1, wc = wave & 1;
  const ushort* Ab = Abf + (size_t)b * NN * NM;
  const ushort* Bb = K3T + (size_t)b * NN * NM;
  f32x4 acc[4][4] = {};
  int srow = t >> 1;
  int sch0 = (t & 1) * 4;
  for (int k0 = 0; k0 < NM; k0 += 64) {
    #pragma unroll
    for (int cc = 0; cc < 4; ++cc) {
      int ch = sch0 + cc;
      int4v a = *(const int4v*)(Ab + (size_t)(bi + srow) * NM + k0 + ch * 8);
      int4v bv = *(const int4v*)(Bb + (size_t)(bj + srow) * NM + k0 + ch * 8);
      int sw = (ch * 16) ^ ((srow & 7) << 4);
      *(int4v*)((char*)As + srow * 128 + sw) = a;
      *(int4v*)((char*)Bs + srow * 128 + sw) = bv;
    }
    __syncthreads();
    #pragma unroll
    for (int kk = 0; kk < 2; ++kk) {
      int koff = kk * 64 + (lane >> 4) * 16;   // byte offset of this lane's 8 bf16 along K
      bf16x8 af[4], bfv[4];
      #pragma unroll
      for (int mi = 0; mi < 4; ++mi) {
        int row = wr * 64 + mi * 16 + (lane & 15);
        af[mi] = *(const bf16x8*)((const char*)As + row * 128 + (koff ^ ((row & 7) << 4)));
      }
      #pragma unroll
      for (int nj = 0; nj < 4; ++nj) {
        int row = wc * 64 + nj * 16 + (lane & 15);
        bfv[nj] = *(const bf16x8*)((const char*)Bs + row * 128 + (koff ^ ((row & 7) << 4)));
      }
      #pragma unroll
      for (int mi = 0; mi < 4; ++mi)
        #pragma unroll
        for (int nj = 0; nj < 4; ++nj)
          acc[mi][nj] = __builtin_amdgcn_mfma_f32_16x16x32_bf16(af[mi], bfv[nj], acc[mi][nj], 0, 0, 0);
    }
    __syncthreads();
  }
  // C/D layout: col = lane&15, row = (lane>>4)*4 + reg   [m89-verified]
  int col = lane & 15, rbase = (lane >> 4) * 4;
  #pragma unroll
  for (int mi = 0; mi < 4; ++mi)
    #pragma unroll
    for (int nj = 0; nj < 4; ++nj)
      #pragma unroll
      for (int r = 0; r < 4; ++r)
        attn[((size_t)b * NN + bi + wr * 64 + mi * 16 + rbase + r) * NN
             + bj + wc * 64 + nj * 16 + col] = acc[mi][nj][r];
}

// ---------------- kv zero + split-K kv ----------------
__global__ void kv_zero_kernel(float* __restrict__ kvout) {
  int idx = blockIdx.x * 256 + threadIdx.x;
  if (idx < NB * NM * NC) kvout[idx] = 0.0f;
}

// kv[b][p][c] = sum_j k3[b][p][j] * v[b][c][j]; split over 32 j-slices, atomicAdd
__global__ __launch_bounds__(256) void kv_kernel(
    const float* __restrict__ K3, const float* __restrict__ Vv,
    float* __restrict__ kvout) {
  int b = blockIdx.z, bp = blockIdx.x * 64;
  int j0base = blockIdx.y * (NN / 32);
  __shared__ float Ks[64][33], Vs[64][33];
  int t = threadIdx.x, tx = t & 15, ty = t >> 4;
  int lrow = t >> 2, ljc = (t & 3) * 8;
  float acc[4][4] = {};
  for (int j0 = j0base; j0 < j0base + NN / 32; j0 += 32) {
    float4 a0 = *(const float4*)(K3 + ((size_t)b * NM + bp + lrow) * NN + j0 + ljc);
    float4 a1 = *(const float4*)(K3 + ((size_t)b * NM + bp + lrow) * NN + j0 + ljc + 4);
    float4 v0 = *(const float4*)(Vv + ((size_t)b * NC + lrow) * NN + j0 + ljc);
    float4 v1 = *(const float4*)(Vv + ((size_t)b * NC + lrow) * NN + j0 + ljc + 4);
    Ks[lrow][ljc + 0] = a0.x; Ks[lrow][ljc + 1] = a0.y; Ks[lrow][ljc + 2] = a0.z; Ks[lrow][ljc + 3] = a0.w;
    Ks[lrow][ljc + 4] = a1.x; Ks[lrow][ljc + 5] = a1.y; Ks[lrow][ljc + 6] = a1.z; Ks[lrow][ljc + 7] = a1.w;
    Vs[lrow][ljc + 0] = v0.x; Vs[lrow][ljc + 1] = v0.y; Vs[lrow][ljc + 2] = v0.z; Vs[lrow][ljc + 3] = v0.w;
    Vs[lrow][ljc + 4] = v1.x; Vs[lrow][ljc + 5] = v1.y; Vs[lrow][ljc + 6] = v1.z; Vs[lrow][ljc + 7] = v1.w;
    __syncthreads();
    #pragma unroll
    for (int kk = 0; kk < 32; ++kk) {
      float av_[4], bv_[4];
      #pragma unroll
      for (int i = 0; i < 4; ++i) av_[i] = Ks[(ty << 2) + i][kk];
      #pragma unroll
      for (int j = 0; j < 4; ++j) bv_[j] = Vs[(tx << 2) + j][kk];
      #pragma unroll
      for (int i = 0; i < 4; ++i)
        #pragma unroll
        for (int j = 0; j < 4; ++j) acc[i][j] += av_[i] * bv_[j];
    }
    __syncthreads();
  }
  #pragma unroll
  for (int i = 0; i < 4; ++i)
    #pragma unroll
    for (int j = 0; j < 4; ++j)
      atomicAdd(&kvout[((size_t)b * NM + bp + (ty << 2) + i) * NC + (tx << 2) + j], acc[i][j]);
}

// ---------------- out = gamma*(A@kv) + x ----------------
__global__ __launch_bounds__(256) void out_kernel(
    const float* __restrict__ Ab, const float* __restrict__ kvm,
    const float* __restrict__ x, const float* __restrict__ gamma,
    float* __restrict__ outp) {
  __shared__ float As[32 * 256];
  int blk = blockIdx.x;
  int b = blk / (NN / 32), n0 = (blk % (NN / 32)) * 32;
  int t = threadIdx.x;
  for (int it = 0; it < 32; ++it)
    As[it * 256 + (t ^ (it & 31))] = Ab[((size_t)b * NN + n0 + it) * NM + t];
  __syncthreads();
  int tn = t & 31, cg0 = (t >> 5) * 8;
  float g = gamma[0];
  float acc[8] = {};
  for (int p = 0; p < NM; ++p) {
    float a = As[tn * 256 + (p ^ (tn & 31))];
    #pragma unroll
    for (int qd = 0; qd < 8; ++qd) acc[qd] += a * kvm[((size_t)b * NM + p) * NC + cg0 + qd];
  }
  #pragma unroll
  for (int qd = 0; qd < 8; ++qd) {
    int c = cg0 + qd;
    size_t idx = ((size_t)b * NC + c) * NN + n0 + tn;
    outp[idx] = g * acc[qd] + x[idx];
  }
}

extern "C" void kernel_launch(void* const* d_in, const int* in_sizes, int n_in,
                              void* d_out, int out_size, void* d_ws, size_t ws_size,
                              hipStream_t stream) {
  const float* x     = (const float*)d_in[0];
  const float* wq    = (const float*)d_in[1];
  const float* bq    = (const float*)d_in[2];
  const float* wk    = (const float*)d_in[3];
  const float* bk    = (const float*)d_in[4];
  const float* wv    = (const float*)d_in[5];
  const float* bv    = (const float*)d_in[6];
  const float* gamma = (const float*)d_in[7];
  float* outp = (float*)d_out;                       // [B][C][N]
  float* attn = outp + (size_t)NB * NC * NN;         // [B][N][N]
  float* w = (float*)d_ws;

  float* qw   = w;                 // [B][N][D]    65536
  float* kw   = qw + 65536;        // [B][N][D]    65536
  float* vw   = kw + 65536;        // [B][C][N]    524288
  float* qlw  = vw + 524288;       // [B][M][D]    4096
  float* klw  = qlw + 4096;        // [B][M][D]    4096
  float* k1w  = klw + 4096;        // [B][N][M]    2097152
  float* k2w  = k1w + 2097152;     // [B][M][M]    131072
  float* k3w  = k2w + 131072;      // [B][M][N]    2097152
  float* Abuf = k3w + 2097152;     // [B][N][M]    2097152
  float* Va   = Abuf + 2097152;    // [B][M][M]    131072
  float* Vb   = Va + 131072;       // [B][M][M]    131072
  float* Zb   = Vb + 131072;       // [B][M][M]    131072
  float* T1   = Zb + 131072;       // [B][M][M]    131072
  float* T2   = T1 + 131072;       // [B][M][M]    131072
  float* kvw  = T2 + 131072;       // [B][M][C]    32768
  float* denw = kvw + 32768;       // [1]
  // bf16 buffers aliased onto k1w (dead after A = k1 @ Vinv)
  ushort* Abf = (ushort*)k1w;                  // [B][N][M] bf16  (4 MB)
  ushort* k3T = (ushort*)k1w + 2097152;        // [B][N][M] bf16 (k3^T)

  kv_zero_kernel<<<dim3(128), dim3(256), 0, stream>>>(kvw);
  qkv_kernel<<<dim3(NB * NN / 256), dim3(256), 0, stream>>>(x, wq, bq, wk, bk, wv, bv, qw, kw, vw);
  landmark_kernel<<<dim3(NB * NM * ND / 256), dim3(256), 0, stream>>>(qw, kw, qlw, klw);
  scores_softmax_m<<<dim3(NN / 4, NB), dim3(256), 0, stream>>>(qw, NN, klw, k1w);
  scores_softmax_m<<<dim3(NM / 4, NB), dim3(256), 0, stream>>>(qlw, NM, klw, k2w);
  scores_softmax_n<<<dim3(NM, NB), dim3(256), 0, stream>>>(qlw, kw, k3w);
  denom_kernel<<<dim3(1), dim3(256), 0, stream>>>(k2w, denw);
  vinit_kernel<<<dim3(NB * NM * NM / 256), dim3(256), 0, stream>>>(k2w, denw, Va);

  float* Vc = Va; float* Vn = Vb;
  for (int it = 0; it < 6; ++it) {
    gemm_rk32<<<dim3(8, 8, NB), dim3(256), 0, stream>>>(k2w, Vc, Zb, 0.f, 1.f);     // Z = K@V
    gemm_rk32<<<dim3(8, 8, NB), dim3(256), 0, stream>>>(Zb, Zb, T1, 7.f, -1.f);     // T1 = 7Z - Z@Z
    gemm_rk32<<<dim3(8, 8, NB), dim3(256), 0, stream>>>(Zb, T1, T2, 15.f, -1.f);    // T2 = 15Z - Z@T1
    gemm_rk32<<<dim3(8, 8, NB), dim3(256), 0, stream>>>(Vc, T2, Vn, 3.25f, -0.25f); // V' = 3.25V - 0.25 V@T2
    float* tmp = Vc; Vc = Vn; Vn = tmp;
  }

  gemm_rk<<<dim3(4, NN / 64, NB), dim3(256), 0, stream>>>(k1w, Vc, Abuf, NN, 0.f, 1.f); // A = k1 @ Vinv
  // convert to bf16 (k1w region now dead)
  cvt_bf16_kernel<<<dim3(2048), dim3(256), 0, stream>>>(Abuf, Abf);
  cvt_t_kernel<<<dim3(NN / 32, NM / 32, NB), dim3(256), 0, stream>>>(k3w, k3T);
  gemm_attn_mfma<<<dim3(NN / 128, NN / 128, NB), dim3(256), 0, stream>>>(Abf, k3T, attn);
  kv_kernel<<<dim3(NM / 64, 32, NB), dim3(256), 0, stream>>>(k3w, vw, kvw);
  out_kernel<<<dim3(NB * NN / 32), dim3(256), 0, stream>>>(Abuf, kvw, x, gamma, outp);
}